// Round 1
// baseline (521.246 us; speedup 1.0000x reference)
//
#include <hip/hip_runtime.h>

typedef unsigned short u16;
typedef unsigned int   u32;
typedef float  f32x4  __attribute__((ext_vector_type(4)));
typedef short  s16x8  __attribute__((ext_vector_type(8)));
typedef __bf16 bf16x8 __attribute__((ext_vector_type(8)));

#define GAMMA_C 0.02f     // 1/(2*sigma^2), sigma=5
#define INV_TEMP 10.0f

__device__ __forceinline__ float bf2f(u16 h) {
  union { u32 u; float f; } c; c.u = ((u32)h) << 16; return c.f;
}
__device__ __forceinline__ u16 f2bf(float f) {
  union { float f; u32 u; } c; c.f = f;
  u32 u = c.u;
  return (u16)((u + 0x7fffu + ((u >> 16) & 1u)) >> 16);
}
__device__ __forceinline__ f32x4 mfma16(s16x8 a, s16x8 b, f32x4 c) {
  union { s16x8 s; bf16x8 b; } ua, ub; ua.s = a; ub.s = b;
  return __builtin_amdgcn_mfma_f32_16x16x32_bf16(ua.b, ub.b, c, 0, 0, 0);
}

// ---------------- f32 -> bf16 cast ----------------
__global__ __launch_bounds__(256)
void castk(const float* __restrict__ in, u16* __restrict__ out, int n) {
  int idx = (blockIdx.x * 256 + threadIdx.x) * 8;
  if (idx >= n) return;
  float4 a = *(const float4*)(in + idx);
  float4 b = *(const float4*)(in + idx + 4);
  int4 ov; u16* op = (u16*)&ov;
  op[0]=f2bf(a.x); op[1]=f2bf(a.y); op[2]=f2bf(a.z); op[3]=f2bf(a.w);
  op[4]=f2bf(b.x); op[5]=f2bf(b.y); op[6]=f2bf(b.z); op[7]=f2bf(b.w);
  *(int4*)(out + idx) = ov;
}

// ---------------- bf16 GEMM, C = A * B^T (both [.,K] row-major) ----------------
// 128x128 tile, BK=32, 256 thr (4 waves 2x2, each 64x64 = 4x4 frags of 16x16)
template<int EPI>  // 0: store bf16 to Cb ; 1: store f32 to Cf
__global__ __launch_bounds__(256)
void gemm_bt(const u16* __restrict__ A, const u16* __restrict__ B,
             u16* __restrict__ Cb, float* __restrict__ Cf,
             int M, int N, int K)
{
  __shared__ u16 As[128*32];
  __shared__ u16 Bs[128*32];
  const int tid = threadIdx.x;
  const int lane = tid & 63, wave = tid >> 6;
  const int wr = wave >> 1, wc = wave & 1;
  const int g = lane >> 4, r16 = lane & 15;
  const int tm = blockIdx.y * 128, tn = blockIdx.x * 128;

  f32x4 acc[4][4] = {};

  for (int kt = 0; kt < K; kt += 32) {
    #pragma unroll
    for (int c = 0; c < 2; ++c) {
      int ld  = (tid + c*256) * 16;      // byte offset in 8KB tile
      int row = ld >> 6, b = ld & 63;    // 64B per row
      int sw  = row*64 + (b ^ ((row & 3) << 4));
      *(int4*)((char*)As + sw) =
          *(const int4*)((const char*)A + (size_t)(tm+row)*(K*2) + (kt*2 + b));
      *(int4*)((char*)Bs + sw) =
          *(const int4*)((const char*)B + (size_t)(tn+row)*(K*2) + (kt*2 + b));
    }
    __syncthreads();
    s16x8 af[4], bv[4];
    #pragma unroll
    for (int m = 0; m < 4; ++m) {
      int row = wr*64 + m*16 + r16;
      af[m] = *(const s16x8*)((const char*)As + row*64 + ((g*16) ^ ((row & 3) << 4)));
    }
    #pragma unroll
    for (int n = 0; n < 4; ++n) {
      int row = wc*64 + n*16 + r16;
      bv[n] = *(const s16x8*)((const char*)Bs + row*64 + ((g*16) ^ ((row & 3) << 4)));
    }
    #pragma unroll
    for (int m = 0; m < 4; ++m)
      #pragma unroll
      for (int n = 0; n < 4; ++n)
        acc[m][n] = mfma16(af[m], bv[n], acc[m][n]);
    __syncthreads();
  }

  #pragma unroll
  for (int m = 0; m < 4; ++m)
    #pragma unroll
    for (int n = 0; n < 4; ++n)
      #pragma unroll
      for (int r = 0; r < 4; ++r) {
        int row = tm + wr*64 + m*16 + g*4 + r;   // C/D: col=lane&15, row=(lane>>4)*4+reg
        int col = tn + wc*64 + n*16 + r16;
        if (EPI == 0) Cb[(size_t)row*N + col] = f2bf(acc[m][n][r]);
        else          Cf[(size_t)row*N + col] = acc[m][n][r];
      }
}

// ---------------- BN stats (per half, per column) ----------------
__global__ __launch_bounds__(256)
void bnstats(const u16* __restrict__ H, const float* __restrict__ gam,
             const float* __restrict__ bet, float* __restrict__ scale,
             float* __restrict__ bias)
{
  __shared__ float S[8][32], SS[8][32];
  int tid = threadIdx.x;
  int half = blockIdx.x >> 6;
  int colBase = (blockIdx.x & 63) * 32;
  int col = colBase + (tid & 31);
  int part = tid >> 5;                       // 8 parts x 512 rows
  const u16* Hp = H + (size_t)half*4096*2048 + (size_t)part*512*2048 + col;
  float s = 0.f, ss = 0.f;
  for (int r = 0; r < 512; ++r) {
    float v = bf2f(Hp[(size_t)r*2048]);
    s += v; ss += v*v;
  }
  S[part][tid & 31] = s; SS[part][tid & 31] = ss;
  __syncthreads();
  if (tid < 32) {
    float sum = 0.f, ssum = 0.f;
    #pragma unroll
    for (int p = 0; p < 8; ++p) { sum += S[p][tid]; ssum += SS[p][tid]; }
    float mu  = sum * (1.f/4096.f);
    float var = fmaxf(ssum * (1.f/4096.f) - mu*mu, 0.f);
    int c = colBase + tid;
    float sc = gam[c] * rsqrtf(var + 1e-5f);
    scale[half*2048 + c] = sc;
    bias [half*2048 + c] = bet[c] - mu * sc;
  }
}

// ---------------- BN apply + ReLU (in place, bf16) ----------------
__global__ __launch_bounds__(256)
void bnapply(u16* __restrict__ H, const float* __restrict__ scale,
             const float* __restrict__ bias)
{
  size_t idx = ((size_t)blockIdx.x * 256 + threadIdx.x) * 8;
  int col  = (int)(idx & 2047);
  int half = (int)(idx >> 23);              // (idx>>11)>>12
  int4 hv = *(int4*)((char*)H + idx*2);
  u16* hp = (u16*)&hv;
  const float* sc = scale + half*2048 + col;
  const float* bi = bias  + half*2048 + col;
  #pragma unroll
  for (int j = 0; j < 8; ++j) {
    float v = bf2f(hp[j]) * sc[j] + bi[j];
    hp[j] = f2bf(fmaxf(v, 0.f));
  }
  *(int4*)((char*)H + idx*2) = hv;
}

// ---------------- L2-normalize rows of Zf [8192][128] -> bf16 ----------------
__global__ __launch_bounds__(256)
void normk(const float* __restrict__ Zf, u16* __restrict__ Zb)
{
  int row = blockIdx.x * 16 + (threadIdx.x >> 4);
  int l16 = threadIdx.x & 15;
  const float* zp = Zf + (size_t)row*128 + l16*8;
  float4 v0 = *(const float4*)zp;
  float4 v1 = *(const float4*)(zp + 4);
  float ss = v0.x*v0.x + v0.y*v0.y + v0.z*v0.z + v0.w*v0.w
           + v1.x*v1.x + v1.y*v1.y + v1.z*v1.z + v1.w*v1.w;
  #pragma unroll
  for (int off = 1; off < 16; off <<= 1) ss += __shfl_xor(ss, off);
  float rs = rsqrtf(ss);
  rs = rs * (1.5f - 0.5f * ss * rs * rs);   // one Newton step
  int4 ov; u16* op = (u16*)&ov;
  op[0]=f2bf(v0.x*rs); op[1]=f2bf(v0.y*rs); op[2]=f2bf(v0.z*rs); op[3]=f2bf(v0.w*rs);
  op[4]=f2bf(v1.x*rs); op[5]=f2bf(v1.y*rs); op[6]=f2bf(v1.z*rs); op[7]=f2bf(v1.w*rs);
  *(int4*)((char*)Zb + ((size_t)row*128 + l16*8)*2) = ov;
}

// ---------------- RBF row-sum normalizer: Rinv[i] = 1/(2*T_i - 1) ----------------
__global__ __launch_bounds__(256)
void rker(const float* __restrict__ labels, float* __restrict__ Rinv)
{
  __shared__ float ls[256];
  int i = blockIdx.x * 256 + threadIdx.x;
  float li = labels[i];
  float T = 0.f;
  for (int j0 = 0; j0 < 4096; j0 += 256) {
    __syncthreads();
    ls[threadIdx.x] = labels[j0 + threadIdx.x];
    __syncthreads();
    #pragma unroll 8
    for (int j = 0; j < 256; ++j) {
      float d = li - ls[j];
      T += __expf(-GAMMA_C * d * d);
    }
  }
  Rinv[i] = 1.f / (2.f * T - 1.f);
}

// ---------------- fused sim + online logsumexp + weighted loss ----------------
// 32 rows per block (2 waves x 16 rows), column tiles of 64, double-buffered LDS.
__global__ __launch_bounds__(128)
void lossk(const u16* __restrict__ Zb, const float* __restrict__ labels,
           const float* __restrict__ Rinv, float* __restrict__ lossr)
{
  __shared__ u16 Zr[32*128];
  __shared__ u16 Zc[2][64*128];
  __shared__ float labc[2][64];
  const int tid = threadIdx.x;
  const int lane = tid & 63, wave = tid >> 6;
  const int g = lane >> 4, r16 = lane & 15;
  const int rowBase = blockIdx.x * 32;

  #pragma unroll
  for (int c = 0; c < 4; ++c) {             // stage Zr (8KB, swizzled)
    int ld = (tid + c*128) * 16;
    int row = ld >> 8, b = ld & 255;
    *(int4*)((char*)Zr + row*256 + (b ^ ((row & 7) << 4))) =
        *(const int4*)((const char*)Zb + (size_t)(rowBase+row)*256 + b);
  }
  const int gi0 = rowBase + wave*16 + g*4;
  float labi[4], rin[4];
  #pragma unroll
  for (int r = 0; r < 4; ++r) {
    labi[r] = labels[(gi0 + r) & 4095];
    rin[r]  = Rinv  [(gi0 + r) & 4095];
  }
  #pragma unroll
  for (int c = 0; c < 8; ++c) {             // stage col chunk 0
    int ld = (tid + c*128) * 16;
    int row = ld >> 8, b = ld & 255;
    *(int4*)((char*)Zc[0] + row*256 + (b ^ ((row & 7) << 4))) =
        *(const int4*)((const char*)Zb + (size_t)row*256 + b);
  }
  if (tid < 64) labc[0][tid] = labels[tid];
  __syncthreads();

  float m_s[4], l_s[4], wA[4];
  #pragma unroll
  for (int r = 0; r < 4; ++r) { m_s[r] = -3e38f; l_s[r] = 0.f; wA[r] = 0.f; }

  for (int ch = 0; ch < 128; ++ch) {
    int buf = ch & 1;
    if (ch + 1 < 128) {                     // prefetch next chunk into other buffer
      int cb = (ch+1) * 64;
      #pragma unroll
      for (int c = 0; c < 8; ++c) {
        int ld = (tid + c*128) * 16;
        int row = ld >> 8, b = ld & 255;
        *(int4*)((char*)Zc[buf^1] + row*256 + (b ^ ((row & 7) << 4))) =
            *(const int4*)((const char*)Zb + (size_t)(cb+row)*256 + b);
      }
      if (tid < 64) labc[buf^1][tid] = labels[(cb + tid) & 4095];
    }
    s16x8 af[4];
    const int arow = wave*16 + r16;
    #pragma unroll
    for (int kk = 0; kk < 4; ++kk)
      af[kk] = *(const s16x8*)((const char*)Zr + arow*256 +
                               ((kk*64 + g*16) ^ ((arow & 7) << 4)));
    float sv[4][4];
    #pragma unroll
    for (int n = 0; n < 4; ++n) {
      f32x4 acc = {0.f,0.f,0.f,0.f};
      const int brow = n*16 + r16;
      #pragma unroll
      for (int kk = 0; kk < 4; ++kk) {
        s16x8 bv = *(const s16x8*)((const char*)Zc[buf] + brow*256 +
                                   ((kk*64 + g*16) ^ ((brow & 7) << 4)));
        acc = mfma16(af[kk], bv, acc);
      }
      int gj = ch*64 + n*16 + r16;
      float labj = labc[buf][n*16 + r16];
      #pragma unroll
      for (int r = 0; r < 4; ++r) {
        float s = acc[r] * INV_TEMP;
        float dl = labi[r] - labj;
        float w = __expf(-GAMMA_C * dl * dl);
        if (gi0 + r == gj) { s = -1e8f; w = 0.f; }   // diag: -INF sim, zero weight
        wA[r] = fmaf(w, s, wA[r]);
        sv[n][r] = s;
      }
    }
    #pragma unroll
    for (int r = 0; r < 4; ++r) {           // online logsumexp update
      float mx = fmaxf(fmaxf(sv[0][r], sv[1][r]), fmaxf(sv[2][r], sv[3][r]));
      #pragma unroll
      for (int off = 1; off < 16; off <<= 1) mx = fmaxf(mx, __shfl_xor(mx, off));
      float mnew = fmaxf(m_s[r], mx);
      float p = __expf(sv[0][r]-mnew) + __expf(sv[1][r]-mnew)
              + __expf(sv[2][r]-mnew) + __expf(sv[3][r]-mnew);
      #pragma unroll
      for (int off = 1; off < 16; off <<= 1) p += __shfl_xor(p, off);
      l_s[r] = l_s[r] * __expf(m_s[r] - mnew) + p;
      m_s[r] = mnew;
    }
    __syncthreads();
  }

  #pragma unroll
  for (int r = 0; r < 4; ++r) {
    float a = wA[r];
    #pragma unroll
    for (int off = 1; off < 16; off <<= 1) a += __shfl_xor(a, off);
    if (r16 == 0)
      lossr[gi0 + r] = a * rin[r] - (m_s[r] + logf(l_s[r]));
  }
}

// ---------------- final deterministic reduce ----------------
__global__ __launch_bounds__(256)
void reducek(const float* __restrict__ lossr, float* __restrict__ out)
{
  __shared__ float s[256];
  float a = 0.f;
  for (int i = threadIdx.x; i < 8192; i += 256) a += lossr[i];
  s[threadIdx.x] = a;
  __syncthreads();
  for (int off = 128; off > 0; off >>= 1) {
    if (threadIdx.x < off) s[threadIdx.x] += s[threadIdx.x + off];
    __syncthreads();
  }
  if (threadIdx.x == 0) out[0] = -s[0] * (1.f/4096.f);
}

extern "C" void kernel_launch(void* const* d_in, const int* in_sizes, int n_in,
                              void* d_out, int out_size, void* d_ws, size_t ws_size,
                              hipStream_t stream) {
  const float* y1     = (const float*)d_in[0];
  const float* y2     = (const float*)d_in[1];
  const float* labels = (const float*)d_in[2];
  const float* W1     = (const float*)d_in[3];
  const float* bng    = (const float*)d_in[4];
  const float* bnb    = (const float*)d_in[5];
  const float* W2     = (const float*)d_in[6];
  float* out = (float*)d_out;
  char* ws = (char*)d_ws;

  // workspace layout (peak ~76 MB); region [0,42MB) is reused after gemm1
  u16*   Ybf   = (u16*)(ws);                    // 33,554,432 B
  u16*   W1bf  = (u16*)(ws + 33554432);         //  8,388,608 B
  u16*   W2bf  = (u16*)(ws + 41943040);         //    524,288 B
  u16*   Hraw  = (u16*)(ws + 42467328);         // 33,554,432 B
  float* Zf    = (float*)(ws);                  // overlays Ybf (dead after gemm1)
  u16*   Zbf   = (u16*)(ws + 4194304);
  float* Rinv  = (float*)(ws + 6291456);
  float* lossr = (float*)(ws + 6307840);
  float* scale = (float*)(ws + 33554432);       // overlays W1bf (dead after gemm1)
  float* biasv = (float*)(ws + 33554432 + 16384);

  castk<<<4096, 256, 0, stream>>>(y1, Ybf,           8388608);
  castk<<<4096, 256, 0, stream>>>(y2, Ybf + 8388608, 8388608);
  castk<<<2048, 256, 0, stream>>>(W1, W1bf,          4194304);
  castk<<< 128, 256, 0, stream>>>(W2, W2bf,           262144);

  gemm_bt<0><<<dim3(16,64), 256, 0, stream>>>(Ybf,  W1bf, Hraw, nullptr, 8192, 2048, 2048);
  bnstats<<<128, 256, 0, stream>>>(Hraw, bng, bnb, scale, biasv);
  bnapply<<<8192, 256, 0, stream>>>(Hraw, scale, biasv);
  gemm_bt<1><<<dim3(1,64), 256, 0, stream>>>(Hraw, W2bf, nullptr, Zf, 8192, 128, 2048);
  normk<<<512, 256, 0, stream>>>(Zf, Zbf);
  rker<<<16, 256, 0, stream>>>(labels, Rinv);
  lossk<<<256, 128, 0, stream>>>(Zbf, labels, Rinv, lossr);
  reducek<<<1, 256, 0, stream>>>(lossr, out);
}

// Round 2
// 321.060 us; speedup vs baseline: 1.6235x; 1.6235x over previous
//
#include <hip/hip_runtime.h>

typedef unsigned short u16;
typedef unsigned int   u32;
typedef float  f32x4  __attribute__((ext_vector_type(4)));
typedef short  s16x8  __attribute__((ext_vector_type(8)));
typedef __bf16 bf16x8 __attribute__((ext_vector_type(8)));

#define GAMMA_C 0.02f     // 1/(2*sigma^2), sigma=5
#define NSPLIT 8

__device__ __forceinline__ float bf2f(u16 h) {
  union { u32 u; float f; } c; c.u = ((u32)h) << 16; return c.f;
}
__device__ __forceinline__ u16 f2bf(float f) {
  union { float f; u32 u; } c; c.f = f;
  u32 u = c.u;
  return (u16)((u + 0x7fffu + ((u >> 16) & 1u)) >> 16);
}
__device__ __forceinline__ f32x4 mfma16(s16x8 a, s16x8 b, f32x4 c) {
  union { s16x8 s; bf16x8 b; } ua, ub; ua.s = a; ub.s = b;
  return __builtin_amdgcn_mfma_f32_16x16x32_bf16(ua.b, ub.b, c, 0, 0, 0);
}
__device__ __forceinline__ void gload_lds16(const void* g, void* l) {
  __builtin_amdgcn_global_load_lds(
      (__attribute__((address_space(1))) const void*)g,
      (__attribute__((address_space(3))) void*)l, 16, 0, 0);
}

// ---------------- f32 -> bf16 cast ----------------
__global__ __launch_bounds__(256)
void castk(const float* __restrict__ in, u16* __restrict__ out, int n) {
  int idx = (blockIdx.x * 256 + threadIdx.x) * 8;
  if (idx >= n) return;
  float4 a = *(const float4*)(in + idx);
  float4 b = *(const float4*)(in + idx + 4);
  int4 ov; u16* op = (u16*)&ov;
  op[0]=f2bf(a.x); op[1]=f2bf(a.y); op[2]=f2bf(a.z); op[3]=f2bf(a.w);
  op[4]=f2bf(b.x); op[5]=f2bf(b.y); op[6]=f2bf(b.z); op[7]=f2bf(b.w);
  *(int4*)(out + idx) = ov;
}

// ---------------- bf16 GEMM, C = A * B^T (both [.,K] row-major) ----------------
// 128x128 tile, BK=64, global_load_lds(16B) staging with pre-swizzled source.
// Split-K via blockIdx.z (kLen per split). EPI 0: bf16 out; EPI 1: f32 partials.
template<int EPI>
__global__ __launch_bounds__(256)
void gemm_bt(const u16* __restrict__ A, const u16* __restrict__ B,
             u16* __restrict__ Cb, float* __restrict__ Cf,
             int M, int N, int K, int kLen)
{
  __shared__ u16 As[128*64];
  __shared__ u16 Bs[128*64];
  const int tid = threadIdx.x;
  const int lane = tid & 63, wave = tid >> 6;
  const int wr = wave >> 1, wc = wave & 1;
  const int g = lane >> 4, r16 = lane & 15;
  const int tm = blockIdx.y * 128, tn = blockIdx.x * 128;
  const int kOff = blockIdx.z * kLen;

  f32x4 acc[4][4] = {};

  for (int kt = kOff; kt < kOff + kLen; kt += 64) {
    #pragma unroll
    for (int c = 0; c < 4; ++c) {
      int ld  = (tid + c*256) * 16;       // byte offset in 16KB tile
      int row = ld >> 7, b = ld & 127;    // 128B per row
      int bs  = b ^ ((row & 7) << 4);     // inverse-swizzled SOURCE, linear DEST
      gload_lds16((const char*)A + (size_t)(tm+row)*(K*2) + (kt*2 + bs),
                  (char*)As + (wave*64 + c*256)*16);
      gload_lds16((const char*)B + (size_t)(tn+row)*(K*2) + (kt*2 + bs),
                  (char*)Bs + (wave*64 + c*256)*16);
    }
    __syncthreads();
    #pragma unroll
    for (int kk = 0; kk < 2; ++kk) {
      s16x8 af[4], bv[4];
      #pragma unroll
      for (int m = 0; m < 4; ++m) {
        int row = wr*64 + m*16 + r16;
        af[m] = *(const s16x8*)((const char*)As + row*128 +
                                ((kk*64 + g*16) ^ ((row & 7) << 4)));
      }
      #pragma unroll
      for (int n = 0; n < 4; ++n) {
        int row = wc*64 + n*16 + r16;
        bv[n] = *(const s16x8*)((const char*)Bs + row*128 +
                                ((kk*64 + g*16) ^ ((row & 7) << 4)));
      }
      #pragma unroll
      for (int m = 0; m < 4; ++m)
        #pragma unroll
        for (int n = 0; n < 4; ++n)
          acc[m][n] = mfma16(af[m], bv[n], acc[m][n]);
    }
    __syncthreads();
  }

  float* Cfo = Cf + (size_t)blockIdx.z * ((size_t)M * (size_t)N);
  #pragma unroll
  for (int m = 0; m < 4; ++m)
    #pragma unroll
    for (int n = 0; n < 4; ++n)
      #pragma unroll
      for (int r = 0; r < 4; ++r) {
        int row = tm + wr*64 + m*16 + g*4 + r;   // C/D: col=lane&15, row=(lane>>4)*4+reg
        int col = tn + wc*64 + n*16 + r16;
        if (EPI == 0) Cb[(size_t)row*N + col] = f2bf(acc[m][n][r]);
        else          Cfo[(size_t)row*N + col] = acc[m][n][r];
      }
}

// ---------------- BN stats (per half, per column) ----------------
__global__ __launch_bounds__(256)
void bnstats(const u16* __restrict__ H, const float* __restrict__ gam,
             const float* __restrict__ bet, float* __restrict__ scale,
             float* __restrict__ bias)
{
  __shared__ float S[8][32], SS[8][32];
  int tid = threadIdx.x;
  int half = blockIdx.x >> 6;
  int colBase = (blockIdx.x & 63) * 32;
  int col = colBase + (tid & 31);
  int part = tid >> 5;                       // 8 parts x 512 rows
  const u16* Hp = H + (size_t)half*4096*2048 + (size_t)part*512*2048 + col;
  float s = 0.f, ss = 0.f;
  for (int r = 0; r < 512; ++r) {
    float v = bf2f(Hp[(size_t)r*2048]);
    s += v; ss += v*v;
  }
  S[part][tid & 31] = s; SS[part][tid & 31] = ss;
  __syncthreads();
  if (tid < 32) {
    float sum = 0.f, ssum = 0.f;
    #pragma unroll
    for (int p = 0; p < 8; ++p) { sum += S[p][tid]; ssum += SS[p][tid]; }
    float mu  = sum * (1.f/4096.f);
    float var = fmaxf(ssum * (1.f/4096.f) - mu*mu, 0.f);
    int c = colBase + tid;
    float sc = gam[c] * rsqrtf(var + 1e-5f);
    scale[half*2048 + c] = sc;
    bias [half*2048 + c] = bet[c] - mu * sc;
  }
}

// ---------------- BN apply + ReLU (in place, bf16) ----------------
__global__ __launch_bounds__(256)
void bnapply(u16* __restrict__ H, const float* __restrict__ scale,
             const float* __restrict__ bias)
{
  size_t idx = ((size_t)blockIdx.x * 256 + threadIdx.x) * 8;
  int col  = (int)(idx & 2047);
  int half = (int)(idx >> 23);
  int4 hv = *(int4*)((char*)H + idx*2);
  u16* hp = (u16*)&hv;
  const float* sc = scale + half*2048 + col;
  const float* bi = bias  + half*2048 + col;
  #pragma unroll
  for (int j = 0; j < 8; ++j) {
    float v = bf2f(hp[j]) * sc[j] + bi[j];
    hp[j] = f2bf(fmaxf(v, 0.f));
  }
  *(int4*)((char*)H + idx*2) = hv;
}

// ---------------- sum 4 K-split partials + L2-normalize rows -> bf16 ----------------
__global__ __launch_bounds__(256)
void normk(const float* __restrict__ Zp, u16* __restrict__ Zb)
{
  int row = blockIdx.x * 16 + (threadIdx.x >> 4);
  int l16 = threadIdx.x & 15;
  size_t off = (size_t)row*128 + l16*8;
  f32x4 v0 = {0.f,0.f,0.f,0.f}, v1 = {0.f,0.f,0.f,0.f};
  #pragma unroll
  for (int s = 0; s < 4; ++s) {
    const float* zp = Zp + (size_t)s*1048576 + off;
    v0 += *(const f32x4*)zp;
    v1 += *(const f32x4*)(zp + 4);
  }
  float ss = v0[0]*v0[0] + v0[1]*v0[1] + v0[2]*v0[2] + v0[3]*v0[3]
           + v1[0]*v1[0] + v1[1]*v1[1] + v1[2]*v1[2] + v1[3]*v1[3];
  #pragma unroll
  for (int off2 = 1; off2 < 16; off2 <<= 1) ss += __shfl_xor(ss, off2);
  float rs = rsqrtf(ss);
  rs = rs * (1.5f - 0.5f * ss * rs * rs);   // one Newton step
  int4 ov; u16* op = (u16*)&ov;
  op[0]=f2bf(v0[0]*rs); op[1]=f2bf(v0[1]*rs); op[2]=f2bf(v0[2]*rs); op[3]=f2bf(v0[3]*rs);
  op[4]=f2bf(v1[0]*rs); op[5]=f2bf(v1[1]*rs); op[6]=f2bf(v1[2]*rs); op[7]=f2bf(v1[3]*rs);
  *(int4*)((char*)Zb + off*2) = ov;
}

// ---------------- RBF row-sum normalizer: Rinv[i] = 1/(2*T_i - 1) ----------------
__global__ __launch_bounds__(256)
void rker(const float* __restrict__ labels, float* __restrict__ Rinv)
{
  __shared__ float ls[256];
  int i = blockIdx.x * 256 + threadIdx.x;
  float li = labels[i];
  float T = 0.f;
  for (int j0 = 0; j0 < 4096; j0 += 256) {
    __syncthreads();
    ls[threadIdx.x] = labels[j0 + threadIdx.x];
    __syncthreads();
    #pragma unroll 8
    for (int j = 0; j < 256; ++j) {
      float d = li - ls[j];
      T += __expf(-GAMMA_C * d * d);
    }
  }
  Rinv[i] = 1.f / (2.f * T - 1.f);
}

// ---------------- fused sim + fixed-max LSE partials + weighted score sum ----------
// One wave per block; 32 rows (2 x 16-row MFMA B-frags); 1024-column split.
// Swapped operands: lane owns row i = r16 (per iset); no LDS, no barriers.
// Partials: l = sum_j exp(s-10), wA = sum_j w * (s/10); combined later.
__global__ __launch_bounds__(64)
void lossk(const u16* __restrict__ Zb, const float* __restrict__ labels,
           float* __restrict__ lbuf, float* __restrict__ wbuf)
{
  const int lane = threadIdx.x & 63;
  const int g = lane >> 4, r16 = lane & 15;
  const int split = blockIdx.x;
  const int rowBase = blockIdx.y * 32;
  const int colBase = split * 1024;

  s16x8 zr[2][4];
  float li[2];
  #pragma unroll
  for (int is = 0; is < 2; ++is) {
    int i = rowBase + is*16 + r16;
    li[is] = labels[i & 4095];
    #pragma unroll
    for (int kk = 0; kk < 4; ++kk)
      zr[is][kk] = *(const s16x8*)((const char*)Zb + (size_t)i*256 + kk*64 + g*16);
  }

  float l[2]  = {0.f, 0.f};
  float wA[2] = {0.f, 0.f};

  for (int ch = 0; ch < 16; ++ch) {
    int jb = colBase + ch*64;
    #pragma unroll
    for (int n = 0; n < 4; ++n) {
      int jrow = jb + n*16;
      const char* zcp = (const char*)Zb + (size_t)(jrow + r16)*256 + g*16;
      s16x8 a0 = *(const s16x8*)(zcp);
      s16x8 a1 = *(const s16x8*)(zcp +  64);
      s16x8 a2 = *(const s16x8*)(zcp + 128);
      s16x8 a3 = *(const s16x8*)(zcp + 192);
      f32x4 labj = *(const f32x4*)(labels + ((jb & 4095) + n*16 + g*4));
      f32x4 acc0 = {0.f,0.f,0.f,0.f};
      f32x4 acc1 = {0.f,0.f,0.f,0.f};
      acc0 = mfma16(a0, zr[0][0], acc0);
      acc0 = mfma16(a1, zr[0][1], acc0);
      acc0 = mfma16(a2, zr[0][2], acc0);
      acc0 = mfma16(a3, zr[0][3], acc0);
      acc1 = mfma16(a0, zr[1][0], acc1);
      acc1 = mfma16(a1, zr[1][1], acc1);
      acc1 = mfma16(a2, zr[1][2], acc1);
      acc1 = mfma16(a3, zr[1][3], acc1);
      #pragma unroll
      for (int r = 0; r < 4; ++r) {
        int j = jrow + g*4 + r;
        #pragma unroll
        for (int is = 0; is < 2; ++is) {
          float d = (is ? acc1[r] : acc0[r]);     // raw dot; s = 10*d
          bool diag = (rowBase + is*16 + r16) == j;
          float e  = __expf(fmaf(d, 10.f, -10.f)); // exp(s - 10), s <= ~10
          float dl = li[is] - labj[r];
          float w  = __expf(-GAMMA_C * dl * dl);
          e = diag ? 0.f : e;
          w = diag ? 0.f : w;
          l[is] += e;
          wA[is] = fmaf(w, d, wA[is]);             // accumulate w * (s/10)
        }
      }
    }
  }

  #pragma unroll
  for (int is = 0; is < 2; ++is) {
    float lv = l[is], wv = wA[is];
    lv += __shfl_xor(lv, 16); lv += __shfl_xor(lv, 32);
    wv += __shfl_xor(wv, 16); wv += __shfl_xor(wv, 32);
    if (g == 0) {
      int i = rowBase + is*16 + r16;
      lbuf[split*8192 + i] = lv;
      wbuf[split*8192 + i] = wv;
    }
  }
}

// ---------------- combine split partials -> per-row loss ----------------
__global__ __launch_bounds__(256)
void combinek(const float* __restrict__ lbuf, const float* __restrict__ wbuf,
              const float* __restrict__ Rinv, float* __restrict__ lossr)
{
  int i = blockIdx.x * 256 + threadIdx.x;   // grid 32
  float ls = 0.f, ws = 0.f;
  #pragma unroll
  for (int s = 0; s < NSPLIT; ++s) {
    ls += lbuf[s*8192 + i];
    ws += wbuf[s*8192 + i];
  }
  lossr[i] = ws * 10.f * Rinv[i & 4095] - (10.f + logf(ls));
}

// ---------------- final deterministic reduce ----------------
__global__ __launch_bounds__(256)
void reducek(const float* __restrict__ lossr, float* __restrict__ out)
{
  __shared__ float s[256];
  float a = 0.f;
  for (int i = threadIdx.x; i < 8192; i += 256) a += lossr[i];
  s[threadIdx.x] = a;
  __syncthreads();
  for (int off = 128; off > 0; off >>= 1) {
    if (threadIdx.x < off) s[threadIdx.x] += s[threadIdx.x + off];
    __syncthreads();
  }
  if (threadIdx.x == 0) out[0] = -s[0] * (1.f/4096.f);
}

extern "C" void kernel_launch(void* const* d_in, const int* in_sizes, int n_in,
                              void* d_out, int out_size, void* d_ws, size_t ws_size,
                              hipStream_t stream) {
  const float* y1     = (const float*)d_in[0];
  const float* y2     = (const float*)d_in[1];
  const float* labels = (const float*)d_in[2];
  const float* W1     = (const float*)d_in[3];
  const float* bng    = (const float*)d_in[4];
  const float* bnb    = (const float*)d_in[5];
  const float* W2     = (const float*)d_in[6];
  float* out = (float*)d_out;
  char* ws = (char*)d_ws;

  // workspace layout (peak ~76 MB); region [0,42MB) reused after gemm1
  u16*   Ybf   = (u16*)(ws);                    // 32 MB
  u16*   W1bf  = (u16*)(ws + 33554432);         //  8 MB
  u16*   W2bf  = (u16*)(ws + 41943040);         // 512 KB
  u16*   Hraw  = (u16*)(ws + 42467328);         // 32 MB
  // after gemm1 (overlays Ybf / W1bf regions):
  float* Zp    = (float*)(ws);                  // 16 MB: [4][8192][128] f32
  u16*   Zbf   = (u16*)(ws + 16777216);         //  2 MB
  float* Rinv  = (float*)(ws + 18874368);       // 16 KB
  float* lbuf  = (float*)(ws + 18890752);       // 256 KB
  float* wbuf  = (float*)(ws + 19152896);       // 256 KB
  float* lossr = (float*)(ws + 19415040);       // 32 KB
  float* scale = (float*)(ws + 33554432);       // 16 KB (in dead W1bf)
  float* biasv = (float*)(ws + 33570816);       // 16 KB

  castk<<<4096, 256, 0, stream>>>(y1, Ybf,           8388608);
  castk<<<4096, 256, 0, stream>>>(y2, Ybf + 8388608, 8388608);
  castk<<<2048, 256, 0, stream>>>(W1, W1bf,          4194304);
  castk<<< 128, 256, 0, stream>>>(W2, W2bf,           262144);

  gemm_bt<0><<<dim3(16,64,1), 256, 0, stream>>>(Ybf,  W1bf, Hraw, nullptr,
                                                8192, 2048, 2048, 2048);
  bnstats<<<128, 256, 0, stream>>>(Hraw, bng, bnb, scale, biasv);
  bnapply<<<8192, 256, 0, stream>>>(Hraw, scale, biasv);
  gemm_bt<1><<<dim3(1,64,4), 256, 0, stream>>>(Hraw, W2bf, nullptr, Zp,
                                               8192, 128, 2048, 512);
  normk<<<512, 256, 0, stream>>>(Zp, Zbf);
  rker<<<16, 256, 0, stream>>>(labels, Rinv);
  lossk<<<dim3(NSPLIT, 256), 64, 0, stream>>>(Zbf, labels, lbuf, wbuf);
  combinek<<<32, 256, 0, stream>>>(lbuf, wbuf, Rinv, lossr);
  reducek<<<1, 256, 0, stream>>>(lossr, out);
}

// Round 3
// 215.684 us; speedup vs baseline: 2.4167x; 1.4886x over previous
//
#include <hip/hip_runtime.h>

typedef unsigned short u16;
typedef unsigned int   u32;
typedef float  f32x4  __attribute__((ext_vector_type(4)));
typedef short  s16x8  __attribute__((ext_vector_type(8)));
typedef __bf16 bf16x8 __attribute__((ext_vector_type(8)));

#define GAMMA_C 0.02f     // 1/(2*sigma^2), sigma=5
#define NSPLIT 8

__device__ __forceinline__ float bf2f(u16 h) {
  union { u32 u; float f; } c; c.u = ((u32)h) << 16; return c.f;
}
__device__ __forceinline__ u16 f2bf(float f) {
  union { float f; u32 u; } c; c.f = f;
  u32 u = c.u;
  return (u16)((u + 0x7fffu + ((u >> 16) & 1u)) >> 16);
}
__device__ __forceinline__ f32x4 mfma16(s16x8 a, s16x8 b, f32x4 c) {
  union { s16x8 s; bf16x8 b; } ua, ub; ua.s = a; ub.s = b;
  return __builtin_amdgcn_mfma_f32_16x16x32_bf16(ua.b, ub.b, c, 0, 0, 0);
}
__device__ __forceinline__ void gload_lds16(const void* g, void* l) {
  __builtin_amdgcn_global_load_lds(
      (__attribute__((address_space(1))) const void*)g,
      (__attribute__((address_space(3))) void*)l, 16, 0, 0);
}

// ---------------- f32 -> bf16 casts ----------------
__global__ __launch_bounds__(256)
void castall(const float* __restrict__ y1, const float* __restrict__ y2,
             const float* __restrict__ W1, u16* __restrict__ Ybf,
             u16* __restrict__ W1bf) {
  int b = blockIdx.x;
  const float* src; u16* dst; int off;
  if (b < 4096)      { src = y1; dst = Ybf;           off = b; }
  else if (b < 8192) { src = y2; dst = Ybf + 8388608; off = b - 4096; }
  else               { src = W1; dst = W1bf;          off = b - 8192; }
  int idx = (off * 256 + threadIdx.x) * 8;
  float4 a = *(const float4*)(src + idx);
  float4 c = *(const float4*)(src + idx + 4);
  int4 ov; u16* op = (u16*)&ov;
  op[0]=f2bf(a.x); op[1]=f2bf(a.y); op[2]=f2bf(a.z); op[3]=f2bf(a.w);
  op[4]=f2bf(c.x); op[5]=f2bf(c.y); op[6]=f2bf(c.z); op[7]=f2bf(c.w);
  *(int4*)(dst + idx) = ov;
}

__global__ __launch_bounds__(256)
void castk(const float* __restrict__ in, u16* __restrict__ out) {
  int idx = (blockIdx.x * 256 + threadIdx.x) * 8;
  float4 a = *(const float4*)(in + idx);
  float4 b = *(const float4*)(in + idx + 4);
  int4 ov; u16* op = (u16*)&ov;
  op[0]=f2bf(a.x); op[1]=f2bf(a.y); op[2]=f2bf(a.z); op[3]=f2bf(a.w);
  op[4]=f2bf(b.x); op[5]=f2bf(b.y); op[6]=f2bf(b.z); op[7]=f2bf(b.w);
  *(int4*)(out + idx) = ov;
}

// ============ gemm1: C = A * B^T, 256x256 tile, BK=64, 8-wave deep pipeline ======
// A [8192][2048] bf16, B [2048][2048] bf16, C bf16; BN col-partials fused.
// LDS: [buf][kk][256 rows][32 k] per operand (2 x 2 x 16KB x 2 = 128KB).
#define SWZ(row) ((((row) >> 1) & 3) << 4)

#define STAGE(ARR, BASE, TOFF, KT, KK, BUF) do {                                   \
  _Pragma("unroll")                                                                \
  for (int c_ = 0; c_ < 2; ++c_) {                                                 \
    int e_ = tid + c_*512; int row_ = e_ >> 2;                                     \
    int bs_ = ((e_ & 3) * 16) ^ SWZ(row_);                                         \
    gload_lds16((const char*)(BASE) + (size_t)((TOFF) + row_)*4096 + (KT)*2 + (KK)*64 + bs_, \
                (char*)&ARR[BUF][KK][0] + (c_*512 + wave*64)*16);                  \
  }                                                                                \
} while (0)

#define LDA(KK, MH, BUF) do {                                                      \
  _Pragma("unroll")                                                                \
  for (int m_ = 0; m_ < 4; ++m_) {                                                 \
    int row_ = wr*128 + ((MH)*4 + m_)*16 + r16;                                    \
    af[m_] = *(const s16x8*)((const char*)&As[BUF][KK][0] + row_*64 + ((g*16) ^ SWZ(row_))); \
  }                                                                                \
  _Pragma("unroll")                                                                \
  for (int n_ = 0; n_ < 4; ++n_) {                                                 \
    int row_ = wc*64 + n_*16 + r16;                                                \
    bv[n_] = *(const s16x8*)((const char*)&Bs[BUF][KK][0] + row_*64 + ((g*16) ^ SWZ(row_))); \
  }                                                                                \
} while (0)

#define MM(MH) do {                                                                \
  __builtin_amdgcn_s_setprio(1);                                                   \
  _Pragma("unroll")                                                                \
  for (int m_ = 0; m_ < 4; ++m_)                                                   \
    _Pragma("unroll")                                                              \
    for (int n_ = 0; n_ < 4; ++n_)                                                 \
      acc[(MH)*4 + m_][n_] = mfma16(af[m_], bv[n_], acc[(MH)*4 + m_][n_]);         \
  __builtin_amdgcn_s_setprio(0);                                                   \
} while (0)

#define BAR() __builtin_amdgcn_s_barrier()
#define VMW(N) asm volatile("s_waitcnt vmcnt(" #N ")" ::: "memory")

__global__ __launch_bounds__(512, 2)
void gemm1(const u16* __restrict__ A, const u16* __restrict__ B,
           u16* __restrict__ C, float* __restrict__ psum, float* __restrict__ psumsq)
{
  __shared__ u16 As[2][2][256*32];
  __shared__ u16 Bs[2][2][256*32];
  const int tid = threadIdx.x;
  const int lane = tid & 63, wave = tid >> 6;   // 8 waves
  const int wr = wave >> 2, wc = wave & 3;      // 2 x 4
  const int g = lane >> 4, r16 = lane & 15;
  const int bx = blockIdx.x & 7, by = blockIdx.x >> 3;  // XCD-aware: xcd owns one bx
  const int tm = by * 256, tn = bx * 256;

  f32x4 acc[8][4] = {};
  s16x8 af[4], bv[4];

  // prologue: stage tile 0 fully; retire kk0 halves, keep kk1 in flight
  STAGE(As, A, tm, 0, 0, 0); STAGE(Bs, B, tn, 0, 0, 0);
  STAGE(As, A, tm, 0, 1, 0); STAGE(Bs, B, tn, 0, 1, 0);
  VMW(4); BAR();

  // main loop: 31 tiles with staging of t+1 (one half-tile per phase)
  for (int t = 0; t < 31; ++t) {
    const int cur = t & 1, nxt = cur ^ 1;
    const int kt2 = t*64 + 64;
    // phase 1 (kk0, m-half 0)
    LDA(0, 0, cur);  STAGE(As, A, tm, kt2, 0, nxt);
    BAR();  MM(0);  BAR();
    // phase 2 (kk0, m-half 1) — retire this tile's kk1 halves
    LDA(0, 1, cur);  STAGE(Bs, B, tn, kt2, 0, nxt);
    BAR();  MM(1);  VMW(4);  BAR();
    // phase 3 (kk1, m-half 0)
    LDA(1, 0, cur);  STAGE(As, A, tm, kt2, 1, nxt);
    BAR();  MM(0);  BAR();
    // phase 4 (kk1, m-half 1) — retire next tile's kk0 halves
    LDA(1, 1, cur);  STAGE(Bs, B, tn, kt2, 1, nxt);
    BAR();  MM(1);  VMW(4);  BAR();
  }
  // tail: tile 31 in buf 1, no staging
  LDA(0, 0, 1);  BAR();  MM(0);  BAR();
  LDA(0, 1, 1);  BAR();  MM(1);  VMW(0);  BAR();
  LDA(1, 0, 1);  BAR();  MM(0);  BAR();
  LDA(1, 1, 1);  BAR();  MM(1);  BAR();

  // epilogue: C store (bf16)
  #pragma unroll
  for (int m = 0; m < 8; ++m)
    #pragma unroll
    for (int n = 0; n < 4; ++n)
      #pragma unroll
      for (int r = 0; r < 4; ++r) {
        int row = tm + wr*128 + m*16 + g*4 + r;   // C/D: col=lane&15, row=(lane>>4)*4+reg
        int col = tn + wc*64 + n*16 + r16;
        C[(size_t)row*2048 + col] = f2bf(acc[m][n][r]);
      }

  // BN column partials (sum, sumsq over this block's 256 rows)
  __syncthreads();
  float* sred  = (float*)&As[0][0][0];   // 512 floats
  float* ssred = sred + 512;
  #pragma unroll
  for (int n = 0; n < 4; ++n) {
    float s = 0.f, ss = 0.f;
    #pragma unroll
    for (int m = 0; m < 8; ++m)
      #pragma unroll
      for (int r = 0; r < 4; ++r) { float v = acc[m][n][r]; s += v; ss = fmaf(v, v, ss); }
    s  += __shfl_xor(s, 16);  s  += __shfl_xor(s, 32);
    ss += __shfl_xor(ss, 16); ss += __shfl_xor(ss, 32);
    if (g == 0) {
      sred [wr*256 + wc*64 + n*16 + r16] = s;
      ssred[wr*256 + wc*64 + n*16 + r16] = ss;
    }
  }
  __syncthreads();
  if (tid < 256) {
    psum  [(size_t)by*2048 + tn + tid] = sred [tid] + sred [256 + tid];
    psumsq[(size_t)by*2048 + tn + tid] = ssred[tid] + ssred[256 + tid];
  }
}

// ---------------- finalize BN: scale/bias per half per column ----------------
__global__ __launch_bounds__(256)
void bnfinal(const float* __restrict__ psum, const float* __restrict__ psumsq,
             const float* __restrict__ gam, const float* __restrict__ bet,
             float* __restrict__ scale, float* __restrict__ bias)
{
  int c = blockIdx.x * 256 + threadIdx.x;   // grid 16 -> 4096 = 2 halves x 2048 cols
  int half = c >> 11, col = c & 2047;
  const float* ps  = psum   + (size_t)half*16*2048 + col;
  const float* pss = psumsq + (size_t)half*16*2048 + col;
  float s = 0.f, ss = 0.f;
  #pragma unroll
  for (int b = 0; b < 16; ++b) { s += ps[b*2048]; ss += pss[b*2048]; }
  float mu  = s * (1.f/4096.f);
  float var = fmaxf(ss * (1.f/4096.f) - mu*mu, 0.f);
  float sc = gam[col] * rsqrtf(var + 1e-5f);
  scale[c] = sc;
  bias [c] = bet[col] - mu * sc;
}

// ============ gemm2: Z = relu(BN(H)) * W2^T, BN fused into A staging ============
// 128x128 tile, BK=64, split-K via blockIdx.z; f32 partials out.
__global__ __launch_bounds__(256)
void gemm2f(const u16* __restrict__ Hraw, const u16* __restrict__ W2bf,
            const float* __restrict__ scale, const float* __restrict__ bias,
            float* __restrict__ Zp, int kLen)
{
  __shared__ u16 As[128*64];
  __shared__ u16 Bs[128*64];
  const int tid = threadIdx.x;
  const int lane = tid & 63, wave = tid >> 6;
  const int wr = wave >> 1, wc = wave & 1;
  const int g = lane >> 4, r16 = lane & 15;
  const int tm = blockIdx.y * 128, tn = blockIdx.x * 128;   // tn = 0 (N=128)
  const int kOff = blockIdx.z * kLen;
  const float* scp = scale + (size_t)(tm >> 12) * 2048;
  const float* bip = bias  + (size_t)(tm >> 12) * 2048;

  f32x4 acc[4][4] = {};

  for (int kt = kOff; kt < kOff + kLen; kt += 64) {
    #pragma unroll
    for (int c = 0; c < 4; ++c) {           // B: gload_lds, pre-swizzled source
      int ld = (tid + c*256) * 16;
      int row = ld >> 7, b = ld & 127;
      int bs = b ^ ((row & 7) << 4);
      gload_lds16((const char*)W2bf + (size_t)(tn+row)*4096 + (kt*2 + bs),
                  (char*)Bs + (wave*64 + c*256)*16);
    }
    #pragma unroll
    for (int c = 0; c < 4; ++c) {           // A: reg-stage + BN + ReLU, swizzled ds_write
      int ld = (tid + c*256) * 16;
      int row = ld >> 7, b = ld & 127;
      int kg = kt + (b >> 1);
      int4 hv = *(const int4*)((const char*)Hraw + (size_t)(tm+row)*4096 + kt*2 + b);
      f32x4 s0 = *(const f32x4*)(scp + kg), s1 = *(const f32x4*)(scp + kg + 4);
      f32x4 b0 = *(const f32x4*)(bip + kg), b1 = *(const f32x4*)(bip + kg + 4);
      u16* hp = (u16*)&hv;
      int4 ov; u16* op = (u16*)&ov;
      #pragma unroll
      for (int j = 0; j < 4; ++j)
        op[j]   = f2bf(fmaxf(fmaf(bf2f(hp[j]),   s0[j], b0[j]), 0.f));
      #pragma unroll
      for (int j = 0; j < 4; ++j)
        op[4+j] = f2bf(fmaxf(fmaf(bf2f(hp[4+j]), s1[j], b1[j]), 0.f));
      *(int4*)((char*)As + row*128 + (b ^ ((row & 7) << 4))) = ov;
    }
    __syncthreads();
    #pragma unroll
    for (int kk = 0; kk < 2; ++kk) {
      s16x8 af[4], bv[4];
      #pragma unroll
      for (int m = 0; m < 4; ++m) {
        int row = wr*64 + m*16 + r16;
        af[m] = *(const s16x8*)((const char*)As + row*128 +
                                ((kk*64 + g*16) ^ ((row & 7) << 4)));
      }
      #pragma unroll
      for (int n = 0; n < 4; ++n) {
        int row = wc*64 + n*16 + r16;
        bv[n] = *(const s16x8*)((const char*)Bs + row*128 +
                                ((kk*64 + g*16) ^ ((row & 7) << 4)));
      }
      #pragma unroll
      for (int m = 0; m < 4; ++m)
        #pragma unroll
        for (int n = 0; n < 4; ++n)
          acc[m][n] = mfma16(af[m], bv[n], acc[m][n]);
    }
    __syncthreads();
  }

  float* Cfo = Zp + (size_t)blockIdx.z * (8192*128);
  #pragma unroll
  for (int m = 0; m < 4; ++m)
    #pragma unroll
    for (int n = 0; n < 4; ++n)
      #pragma unroll
      for (int r = 0; r < 4; ++r) {
        int row = tm + wr*64 + m*16 + g*4 + r;
        int col = tn + wc*64 + n*16 + r16;
        Cfo[(size_t)row*128 + col] = acc[m][n][r];
      }
}

// ---------------- sum 4 K-split partials + L2-normalize rows -> bf16 ----------------
__global__ __launch_bounds__(256)
void normk(const float* __restrict__ Zp, u16* __restrict__ Zb)
{
  int row = blockIdx.x * 16 + (threadIdx.x >> 4);
  int l16 = threadIdx.x & 15;
  size_t off = (size_t)row*128 + l16*8;
  f32x4 v0 = {0.f,0.f,0.f,0.f}, v1 = {0.f,0.f,0.f,0.f};
  #pragma unroll
  for (int s = 0; s < 4; ++s) {
    const float* zp = Zp + (size_t)s*1048576 + off;
    v0 += *(const f32x4*)zp;
    v1 += *(const f32x4*)(zp + 4);
  }
  float ss = v0[0]*v0[0] + v0[1]*v0[1] + v0[2]*v0[2] + v0[3]*v0[3]
           + v1[0]*v1[0] + v1[1]*v1[1] + v1[2]*v1[2] + v1[3]*v1[3];
  #pragma unroll
  for (int o = 1; o < 16; o <<= 1) ss += __shfl_xor(ss, o);
  float rs = rsqrtf(ss);
  rs = rs * (1.5f - 0.5f * ss * rs * rs);
  int4 ov; u16* op = (u16*)&ov;
  op[0]=f2bf(v0[0]*rs); op[1]=f2bf(v0[1]*rs); op[2]=f2bf(v0[2]*rs); op[3]=f2bf(v0[3]*rs);
  op[4]=f2bf(v1[0]*rs); op[5]=f2bf(v1[1]*rs); op[6]=f2bf(v1[2]*rs); op[7]=f2bf(v1[3]*rs);
  *(int4*)((char*)Zb + off*2) = ov;
}

// ---------------- fused sim + fixed-max LSE + weighted score + weight-sum ----------
__global__ __launch_bounds__(64)
void lossk(const u16* __restrict__ Zb, const float* __restrict__ labels,
           float* __restrict__ lbuf, float* __restrict__ wbuf, float* __restrict__ sbuf)
{
  const int lane = threadIdx.x & 63;
  const int g = lane >> 4, r16 = lane & 15;
  const int split = blockIdx.x;
  const int rowBase = blockIdx.y * 32;
  const int colBase = split * 1024;

  s16x8 zr[2][4];
  float li[2];
  #pragma unroll
  for (int is = 0; is < 2; ++is) {
    int i = rowBase + is*16 + r16;
    li[is] = labels[i & 4095];
    #pragma unroll
    for (int kk = 0; kk < 4; ++kk)
      zr[is][kk] = *(const s16x8*)((const char*)Zb + (size_t)i*256 + kk*64 + g*16);
  }

  float l[2]  = {0.f, 0.f};
  float wA[2] = {0.f, 0.f};
  float wS[2] = {0.f, 0.f};

  for (int ch = 0; ch < 16; ++ch) {
    int jb = colBase + ch*64;
    #pragma unroll
    for (int n = 0; n < 4; ++n) {
      int jrow = jb + n*16;
      const char* zcp = (const char*)Zb + (size_t)(jrow + r16)*256 + g*16;
      s16x8 a0 = *(const s16x8*)(zcp);
      s16x8 a1 = *(const s16x8*)(zcp +  64);
      s16x8 a2 = *(const s16x8*)(zcp + 128);
      s16x8 a3 = *(const s16x8*)(zcp + 192);
      f32x4 labj = *(const f32x4*)(labels + ((jb & 4095) + n*16 + g*4));
      f32x4 acc0 = {0.f,0.f,0.f,0.f};
      f32x4 acc1 = {0.f,0.f,0.f,0.f};
      acc0 = mfma16(a0, zr[0][0], acc0);
      acc0 = mfma16(a1, zr[0][1], acc0);
      acc0 = mfma16(a2, zr[0][2], acc0);
      acc0 = mfma16(a3, zr[0][3], acc0);
      acc1 = mfma16(a0, zr[1][0], acc1);
      acc1 = mfma16(a1, zr[1][1], acc1);
      acc1 = mfma16(a2, zr[1][2], acc1);
      acc1 = mfma16(a3, zr[1][3], acc1);
      #pragma unroll
      for (int r = 0; r < 4; ++r) {
        int j = jrow + g*4 + r;
        #pragma unroll
        for (int is = 0; is < 2; ++is) {
          float d = (is ? acc1[r] : acc0[r]);       // raw dot; s = 10*d
          bool diag = (rowBase + is*16 + r16) == j;
          float e  = __expf(fmaf(d, 10.f, -10.f));  // exp(s - 10)
          float dl = li[is] - labj[r];
          float w  = __expf(-GAMMA_C * dl * dl);
          e = diag ? 0.f : e;
          w = diag ? 0.f : w;
          l[is] += e;
          wS[is] += w;
          wA[is] = fmaf(w, d, wA[is]);
        }
      }
    }
  }

  #pragma unroll
  for (int is = 0; is < 2; ++is) {
    float lv = l[is], wv = wA[is], sv = wS[is];
    lv += __shfl_xor(lv, 16); lv += __shfl_xor(lv, 32);
    wv += __shfl_xor(wv, 16); wv += __shfl_xor(wv, 32);
    sv += __shfl_xor(sv, 16); sv += __shfl_xor(sv, 32);
    if (g == 0) {
      int i = rowBase + is*16 + r16;
      lbuf[split*8192 + i] = lv;
      wbuf[split*8192 + i] = wv;
      sbuf[split*8192 + i] = sv;
    }
  }
}

// ---------------- combine split partials -> per-row loss ----------------
__global__ __launch_bounds__(256)
void combinek(const float* __restrict__ lbuf, const float* __restrict__ wbuf,
              const float* __restrict__ sbuf, float* __restrict__ lossr)
{
  int i = blockIdx.x * 256 + threadIdx.x;   // grid 32
  float ls = 0.f, ws = 0.f, rs = 0.f;
  #pragma unroll
  for (int s = 0; s < NSPLIT; ++s) {
    ls += lbuf[s*8192 + i];
    ws += wbuf[s*8192 + i];
    rs += sbuf[s*8192 + i];
  }
  lossr[i] = ws * 10.f / rs - (10.f + logf(ls));
}

// ---------------- final deterministic reduce ----------------
__global__ __launch_bounds__(256)
void reducek(const float* __restrict__ lossr, float* __restrict__ out)
{
  __shared__ float s[256];
  float a = 0.f;
  for (int i = threadIdx.x; i < 8192; i += 256) a += lossr[i];
  s[threadIdx.x] = a;
  __syncthreads();
  for (int off = 128; off > 0; off >>= 1) {
    if (threadIdx.x < off) s[threadIdx.x] += s[threadIdx.x + off];
    __syncthreads();
  }
  if (threadIdx.x == 0) out[0] = -s[0] * (1.f/4096.f);
}

extern "C" void kernel_launch(void* const* d_in, const int* in_sizes, int n_in,
                              void* d_out, int out_size, void* d_ws, size_t ws_size,
                              hipStream_t stream) {
  const float* y1     = (const float*)d_in[0];
  const float* y2     = (const float*)d_in[1];
  const float* labels = (const float*)d_in[2];
  const float* W1     = (const float*)d_in[3];
  const float* bng    = (const float*)d_in[4];
  const float* bnb    = (const float*)d_in[5];
  const float* W2     = (const float*)d_in[6];
  float* out = (float*)d_out;
  char* ws = (char*)d_ws;

  // layout (peak 76,021,760 B, same as round 2):
  u16*   Ybf    = (u16*)(ws);                    // [0, 32M)
  u16*   W1bf   = (u16*)(ws + 33554432);         // [32M, 40M)
  float* psum   = (float*)(ws + 41943040);       // 256KB (W2bf slot; dead after bnfinal)
  float* psumsq = (float*)(ws + 41943040 + 262144);
  u16*   W2bf   = (u16*)(ws + 41943040);         // cast AFTER bnfinal
  u16*   Hraw   = (u16*)(ws + 42467328);         // 32MB
  // post-gemm1 (overlays dead Ybf region):
  float* Zp     = (float*)(ws);                  // 16MB [4][8192][128]
  u16*   Zbf    = (u16*)(ws + 16777216);         // 2MB
  float* lbuf   = (float*)(ws + 18874368);       // 256KB
  float* wbuf   = (float*)(ws + 19136512);       // 256KB
  float* sbuf   = (float*)(ws + 19398656);       // 256KB
  float* lossr  = (float*)(ws + 19660800);       // 32KB
  float* scale  = (float*)(ws + 20971520);       // 16KB
  float* biasv  = (float*)(ws + 20987904);       // 16KB

  castall<<<10240, 256, 0, stream>>>(y1, y2, W1, Ybf, W1bf);
  gemm1<<<256, 512, 0, stream>>>(Ybf, W1bf, Hraw, psum, psumsq);
  bnfinal<<<16, 256, 0, stream>>>(psum, psumsq, bng, bnb, scale, biasv);
  castk<<<128, 256, 0, stream>>>(W2, W2bf);
  gemm2f<<<dim3(1,64,4), 256, 0, stream>>>(Hraw, W2bf, scale, biasv, Zp, 512);
  normk<<<512, 256, 0, stream>>>(Zp, Zbf);
  lossk<<<dim3(NSPLIT, 256), 64, 0, stream>>>(Zbf, labels, lbuf, wbuf, sbuf);
  combinek<<<32, 256, 0, stream>>>(lbuf, wbuf, sbuf, lossr);
  reducek<<<1, 256, 0, stream>>>(lossr, out);
}